// Round 4
// baseline (413.654 us; speedup 1.0000x reference)
//
#include <hip/hip_runtime.h>
#include <stdint.h>

// ============================================================================
// ExpertMLP: out = relu(x @ W_fc^T)^2 @ W_proj^T    (fp32 in/out, bf16 MFMA)
// R4: - fp32->bf16 fused into GEMM staging (no cvt prepass at all)
//     - LDS double-buffer, ONE barrier per K-iter
//     - register prefetch distance ~2: loads for tile k+2 issued after the
//       barrier, consumed (vmcnt-waited) only at the NEXT iteration's
//       ds_write -> a full iteration of latency cover, in plain VGPRs so the
//       barrier does not have to drain them (not global_load_lds).
// ws: h[64Mi] bf16 only.
// ============================================================================

#define BM 128
#define BN 128
#define BK 32

typedef __attribute__((ext_vector_type(8))) short bf16x8;   // 8 bf16 = 4 VGPRs
typedef __attribute__((ext_vector_type(4))) float f32x4;    // MFMA C/D

__device__ __forceinline__ unsigned short f2bf(float f) {
    unsigned int u = __float_as_uint(f);
    u += 0x7FFFu + ((u >> 16) & 1u);   // RNE, finite inputs
    return (unsigned short)(u >> 16);
}
__device__ __forceinline__ unsigned int pack2(float lo, float hi) {
    return (unsigned int)f2bf(lo) | ((unsigned int)f2bf(hi) << 16);
}

// --------------------------------------------------------------------------
// C[M,N] = A[M,K] . B[N,K]^T ; AF32/BF32: operand stored fp32 (convert in
// staging) else bf16. RELU2: relu^2 epilogue. OUTBF16: bf16 store else fp32.
// SWIZ 0: GEMM1 grid 32x64 — XCD owns 8 M-strips, column-outer.
// SWIZ 1: GEMM2 grid 8x64  — XCD owns 2 N-cols x 32 M-blocks (B L2-resident).
// --------------------------------------------------------------------------
template<bool AF32, bool BF32, bool RELU2, bool OUTBF16, int SWIZ>
__global__ __launch_bounds__(256, 3)
void gemm_bt(const void* __restrict__ Av, const void* __restrict__ Bv,
             void* __restrict__ Cv, int M, int N, int K)
{
    __shared__ unsigned short sA[2][BM * BK];   // 2 x 8 KiB
    __shared__ unsigned short sB[2][BN * BK];   // 2 x 8 KiB

    const int tid  = threadIdx.x;
    const int lane = tid & 63;
    const int wave = tid >> 6;
    const int wm   = (wave >> 1) * 64;
    const int wn   = (wave & 1) * 64;
    const int quad = lane >> 4;
    const int m16  = lane & 15;

    const int lbid = blockIdx.y * gridDim.x + blockIdx.x;
    int bx, by;
    if (SWIZ == 1) {                  // 512 blocks: xcd -> (2 cols, 32 M-blocks)
        const int xcd = lbid & 7, t = lbid >> 3;       // t in [0,64)
        bx = (xcd & 3) * 2 + (t & 1);                  // [0,8)
        by = (xcd >> 2) * 32 + (t >> 1);               // [0,64)
    } else {                          // 2048 blocks: xcd -> 8 M-strips, col-outer
        const int xcd = lbid & 7, t = lbid >> 3;       // t in [0,256)
        by = xcd * 8 + (t & 7);                        // [0,64)
        bx = t >> 3;                                   // [0,32)
    }

    const long bm0 = (long)by * BM;
    const long bn0 = (long)bx * BN;

    // ---- staging addressing ---------------------------------------------
    // bf16 operand: thread loads 2x uint4 (8 bf16 each): row=tid/4 (+64), col8=(tid&3)*8
    // fp32 operand: thread loads 4x float4: row=tid/8 (+j*32), col4=(tid&7)*4
    const unsigned short* gAb = (const unsigned short*)Av + (bm0 + (tid >> 2)) * (long)K + (tid & 3) * 8;
    const float*          gAf = (const float*)Av          + (bm0 + (tid >> 3)) * (long)K + (tid & 7) * 4;
    const unsigned short* gBb = (const unsigned short*)Bv + (bn0 + (tid >> 2)) * (long)K + (tid & 3) * 8;
    const float*          gBf = (const float*)Bv          + (bn0 + (tid >> 3)) * (long)K + (tid & 7) * 4;

    uint4  rab[2]; float4 raf[4];     // A staging regs (one path used)
    uint4  rbb[2]; float4 rbf[4];     // B staging regs

    auto loadA = [&](int k0) {
        if constexpr (AF32) {
            #pragma unroll
            for (int j = 0; j < 4; j++) raf[j] = *(const float4*)(gAf + (long)j * 32 * K + k0);
        } else {
            #pragma unroll
            for (int j = 0; j < 2; j++) rab[j] = *(const uint4*)(gAb + (long)j * 64 * K + k0);
        }
    };
    auto loadB = [&](int k0) {
        if constexpr (BF32) {
            #pragma unroll
            for (int j = 0; j < 4; j++) rbf[j] = *(const float4*)(gBf + (long)j * 32 * K + k0);
        } else {
            #pragma unroll
            for (int j = 0; j < 2; j++) rbb[j] = *(const uint4*)(gBb + (long)j * 64 * K + k0);
        }
    };
    auto writeA = [&](int p) {
        if constexpr (AF32) {
            #pragma unroll
            for (int j = 0; j < 4; j++) {
                uint2 w; w.x = pack2(raf[j].x, raf[j].y); w.y = pack2(raf[j].z, raf[j].w);
                *(uint2*)&sA[p][((tid >> 3) + j * 32) * BK + (tid & 7) * 4] = w;
            }
        } else {
            *(uint4*)&sA[p][tid * 8]        = rab[0];
            *(uint4*)&sA[p][tid * 8 + 2048] = rab[1];
        }
    };
    auto writeB = [&](int p) {
        if constexpr (BF32) {
            #pragma unroll
            for (int j = 0; j < 4; j++) {
                uint2 w; w.x = pack2(rbf[j].x, rbf[j].y); w.y = pack2(rbf[j].z, rbf[j].w);
                *(uint2*)&sB[p][((tid >> 3) + j * 32) * BK + (tid & 7) * 4] = w;
            }
        } else {
            *(uint4*)&sB[p][tid * 8]        = rbb[0];
            *(uint4*)&sB[p][tid * 8 + 2048] = rbb[1];
        }
    };

    f32x4 acc[4][4];
    #pragma unroll
    for (int i = 0; i < 4; i++)
        #pragma unroll
        for (int j = 0; j < 4; j++)
            acc[i][j] = (f32x4)0.0f;

    const int nk = K / BK;

    // ---- prologue: tile 0 -> buf 0; issue tile 1 loads -------------------
    loadA(0); loadB(0);
    writeA(0); writeB(0);
    __syncthreads();
    if (nk > 1) { loadA(BK); loadB(BK); }

    // ---- main loop: ONE barrier per iteration ----------------------------
    for (int k0 = 0; k0 < nk; k0++) {
        const int p = k0 & 1;

        bf16x8 af[4], bfr[4];
        #pragma unroll
        for (int i = 0; i < 4; i++)
            af[i]  = *(const bf16x8*)&sA[p][(wm + i * 16 + m16) * BK + quad * 8];
        #pragma unroll
        for (int j = 0; j < 4; j++)
            bfr[j] = *(const bf16x8*)&sB[p][(wn + j * 16 + m16) * BK + quad * 8];

        #pragma unroll
        for (int i = 0; i < 4; i++)
            #pragma unroll
            for (int j = 0; j < 4; j++)
                acc[i][j] = __builtin_amdgcn_mfma_f32_16x16x32_bf16(
                    af[i], bfr[j], acc[i][j], 0, 0, 0);

        if (k0 + 1 < nk) {           // vmcnt wait for tile k0+1 lands HERE
            writeA(p ^ 1); writeB(p ^ 1);
        }
        __syncthreads();
        if (k0 + 2 < nk) {           // full-iteration cover for these loads
            loadA((k0 + 2) * BK); loadB((k0 + 2) * BK);
        }
    }

    // ---- epilogue: C/D layout col=lane&15, row=quad*4+reg ----------------
    #pragma unroll
    for (int i = 0; i < 4; i++) {
        #pragma unroll
        for (int j = 0; j < 4; j++) {
            #pragma unroll
            for (int r = 0; r < 4; r++) {
                float v = acc[i][j][r];
                if (RELU2) v = (v > 0.0f) ? v * v : 0.0f;
                const long row = bm0 + wm + i * 16 + quad * 4 + r;
                const long col = bn0 + wn + j * 16 + m16;
                if (OUTBF16)
                    ((unsigned short*)Cv)[row * (long)N + col] = f2bf(v);
                else
                    ((float*)Cv)[row * (long)N + col] = v;
            }
        }
    }
}

extern "C" void kernel_launch(void* const* d_in, const int* in_sizes, int n_in,
                              void* d_out, int out_size, void* d_ws, size_t ws_size,
                              hipStream_t stream) {
    (void)in_sizes; (void)n_in; (void)out_size; (void)ws_size;

    const int T = 8192, DIM = 1024, HID = 4096;

    const float* x     = (const float*)d_in[0];  // [T, DIM]
    const float* W_fc  = (const float*)d_in[1];  // [HID, DIM]
    const float* W_prj = (const float*)d_in[2];  // [DIM, HID]
    float* out = (float*)d_out;                  // [T, DIM]

    unsigned short* h = (unsigned short*)d_ws;   // [T, HID] bf16, 64 MiB

    // GEMM1: h = relu(x . W_fc^T)^2   (A,B fp32 -> staged bf16)
    gemm_bt<true, true, true, true, 0>
        <<<dim3(HID / BN, T / BM), dim3(256), 0, stream>>>(x, W_fc, h, T, HID, DIM);

    // GEMM2: out = h . W_proj^T       (A bf16 from ws, B fp32)
    gemm_bt<false, true, false, false, 1>
        <<<dim3(DIM / BN, T / BM), dim3(256), 0, stream>>>(h, W_prj, out, T, DIM, HID);
}

// Round 5
// 278.813 us; speedup vs baseline: 1.4836x; 1.4836x over previous
//
#include <hip/hip_runtime.h>
#include <stdint.h>

// ============================================================================
// ExpertMLP: out = relu(x @ W_fc^T)^2 @ W_proj^T    (fp32 in/out, bf16 MFMA)
// R5: revert to the proven round-2 m97 structure (global_load_lds width=16,
//     BK=32, two barriers) with ONE change: __launch_bounds__(256,4) to get
//     4 resident blocks/CU (120 regs/lane: 56 VGPR + 64 AGPR <= 128 cap).
//     cvt prepass: 3 exact-grid float4 streaming kernels (no grid-stride
//     branches).
// ws: h[64Mi] | x_bf[16Mi] | wfc_bf[8Mi] | wproj_bf[8Mi] = 96 MiB.
// ============================================================================

#define BM 128
#define BN 128
#define BK 32

typedef __attribute__((ext_vector_type(8))) short bf16x8;   // 8 bf16 = 4 VGPRs
typedef __attribute__((ext_vector_type(4))) float f32x4;    // MFMA C/D

typedef const __attribute__((address_space(1))) unsigned int* gas_u32p;
typedef __attribute__((address_space(3))) unsigned int* las_u32p;

__device__ __forceinline__ void load16_to_lds(const void* gptr, void* lptr) {
    // async global->LDS, 16 B per lane; LDS dst = wave-uniform base + lane*16
    __builtin_amdgcn_global_load_lds((gas_u32p)gptr, (las_u32p)lptr, 16, 0, 0);
}

__device__ __forceinline__ unsigned short f2bf(float f) {
    unsigned int u = __float_as_uint(f);
    u += 0x7FFFu + ((u >> 16) & 1u);   // RNE; finite inputs
    return (unsigned short)(u >> 16);
}

// --------------------------------------------------------------------------
// fp32 -> bf16, exact grid (n4 = elements/4, grid*256 == n4/2), 2 float4/thr
// --------------------------------------------------------------------------
__global__ void cvt_f32_bf16(const float4* __restrict__ src,
                             ushort4* __restrict__ dst)
{
    const int i = (blockIdx.x * blockDim.x + threadIdx.x) * 2;
    #pragma unroll
    for (int j = 0; j < 2; j++) {
        float4 v = src[i + j];
        ushort4 o;
        o.x = f2bf(v.x); o.y = f2bf(v.y); o.z = f2bf(v.z); o.w = f2bf(v.w);
        dst[i + j] = o;
    }
}

// --------------------------------------------------------------------------
// C[M,N] = A[M,K] . B[N,K]^T  (bf16-as-ushort in, fp32 accum)
// RELU2: relu(v)^2 epilogue. OUT_BF16: bf16 store else fp32.
// m97 structure: global_load_lds staging, 2 barriers/iter, 16 MFMA/iter.
// --------------------------------------------------------------------------
template<bool RELU2, bool OUT_BF16>
__global__ __launch_bounds__(256, 4)
void gemm_bt(const unsigned short* __restrict__ A,
             const unsigned short* __restrict__ B,
             void* __restrict__ Cv, int M, int N, int K)
{
    __shared__ unsigned short sA[BM * BK];   // 8 KiB row-major [128][32]
    __shared__ unsigned short sB[BN * BK];   // 8 KiB

    const int tid  = threadIdx.x;
    const int lane = tid & 63;
    const int wave = tid >> 6;
    const int wm   = (wave >> 1) * 64;
    const int wn   = (wave & 1) * 64;
    const int quad = lane >> 4;
    const int m16  = lane & 15;

    const long bm0 = (long)blockIdx.y * BM;
    const long bn0 = (long)blockIdx.x * BN;

    // staging: row = c*64 + tid/4, 16B slot = tid%4; LDS off = c*4096 + tid*16
    const int srow = tid >> 2;
    const int scol = (tid & 3) * 8;

    const unsigned short* gA = A + (bm0 + srow) * (long)K + scol;
    const unsigned short* gB = B + (bn0 + srow) * (long)K + scol;
    char* lA = (char*)sA + tid * 16;
    char* lB = (char*)sB + tid * 16;

    f32x4 acc[4][4];
    #pragma unroll
    for (int i = 0; i < 4; i++)
        #pragma unroll
        for (int j = 0; j < 4; j++)
            acc[i][j] = (f32x4)0.0f;

    for (int k0 = 0; k0 < K; k0 += BK) {
        load16_to_lds(gA + k0,                lA);
        load16_to_lds(gA + 64 * (long)K + k0, lA + 4096);
        load16_to_lds(gB + k0,                lB);
        load16_to_lds(gB + 64 * (long)K + k0, lB + 4096);
        __syncthreads();

        bf16x8 af[4], bfr[4];
        #pragma unroll
        for (int i = 0; i < 4; i++)
            af[i]  = *(const bf16x8*)&sA[(wm + i * 16 + m16) * BK + quad * 8];
        #pragma unroll
        for (int j = 0; j < 4; j++)
            bfr[j] = *(const bf16x8*)&sB[(wn + j * 16 + m16) * BK + quad * 8];

        #pragma unroll
        for (int i = 0; i < 4; i++)
            #pragma unroll
            for (int j = 0; j < 4; j++)
                acc[i][j] = __builtin_amdgcn_mfma_f32_16x16x32_bf16(
                    af[i], bfr[j], acc[i][j], 0, 0, 0);

        __syncthreads();
    }

    // epilogue: C/D layout col=lane&15, row=quad*4+reg (m89/m91)
    #pragma unroll
    for (int i = 0; i < 4; i++) {
        #pragma unroll
        for (int j = 0; j < 4; j++) {
            #pragma unroll
            for (int r = 0; r < 4; r++) {
                float v = acc[i][j][r];
                if (RELU2) v = (v > 0.0f) ? v * v : 0.0f;
                const long row = bm0 + wm + i * 16 + quad * 4 + r;
                const long col = bn0 + wn + j * 16 + m16;
                if (OUT_BF16)
                    ((unsigned short*)Cv)[row * (long)N + col] = f2bf(v);
                else
                    ((float*)Cv)[row * (long)N + col] = v;
            }
        }
    }
}

extern "C" void kernel_launch(void* const* d_in, const int* in_sizes, int n_in,
                              void* d_out, int out_size, void* d_ws, size_t ws_size,
                              hipStream_t stream) {
    (void)in_sizes; (void)n_in; (void)out_size; (void)ws_size;

    const int T = 8192, DIM = 1024, HID = 4096;

    const float* x     = (const float*)d_in[0];  // [T, DIM]
    const float* W_fc  = (const float*)d_in[1];  // [HID, DIM]
    const float* W_prj = (const float*)d_in[2];  // [DIM, HID]
    float* out = (float*)d_out;                  // [T, DIM]

    char* ws = (char*)d_ws;
    unsigned short* h   = (unsigned short*)ws;                  // 64 MiB [T,HID]
    unsigned short* xb  = (unsigned short*)(ws + (64l << 20));  // 16 MiB
    unsigned short* wfb = (unsigned short*)(ws + (80l << 20));  //  8 MiB
    unsigned short* wpb = (unsigned short*)(ws + (88l << 20));  //  8 MiB

    // prepass: fp32 -> bf16 (exact grids, 2 float4/thread)
    cvt_f32_bf16<<<T * DIM   / (256 * 8), 256, 0, stream>>>((const float4*)x,     (ushort4*)xb);
    cvt_f32_bf16<<<HID * DIM / (256 * 8), 256, 0, stream>>>((const float4*)W_fc,  (ushort4*)wfb);
    cvt_f32_bf16<<<DIM * HID / (256 * 8), 256, 0, stream>>>((const float4*)W_prj, (ushort4*)wpb);

    // GEMM1: h = relu(x . W_fc^T)^2  [8192,4096] bf16
    gemm_bt<true, true><<<dim3(HID / BN, T / BM), dim3(256), 0, stream>>>(
        xb, wfb, h, T, HID, DIM);

    // GEMM2: out = h . W_proj^T      [8192,1024] fp32
    gemm_bt<false, false><<<dim3(DIM / BN, T / BM), dim3(256), 0, stream>>>(
        h, wpb, out, T, DIM, HID);
}

// Round 6
// 272.677 us; speedup vs baseline: 1.5170x; 1.0225x over previous
//
#include <hip/hip_runtime.h>
#include <stdint.h>

// ============================================================================
// ExpertMLP: out = relu(x @ W_fc^T)^2 @ W_proj^T    (fp32 in/out, bf16 MFMA)
// R6: m97 structure with BK=64 (halves barrier/staging events per GEMM,
//     32 MFMA per iteration) + single fused cvt prepass kernel.
// ws: h[64Mi] | x_bf[16Mi] | wfc_bf[8Mi] | wproj_bf[8Mi] = 96 MiB.
// ============================================================================

#define BM 128
#define BN 128
#define BK 64

typedef __attribute__((ext_vector_type(8))) short bf16x8;   // 8 bf16 = 4 VGPRs
typedef __attribute__((ext_vector_type(4))) float f32x4;    // MFMA C/D

typedef const __attribute__((address_space(1))) unsigned int* gas_u32p;
typedef __attribute__((address_space(3))) unsigned int* las_u32p;

__device__ __forceinline__ void load16_to_lds(const void* gptr, void* lptr) {
    // async global->LDS, 16 B per lane; LDS dst = wave-uniform base + lane*16
    __builtin_amdgcn_global_load_lds((gas_u32p)gptr, (las_u32p)lptr, 16, 0, 0);
}

__device__ __forceinline__ unsigned short f2bf(float f) {
    unsigned int u = __float_as_uint(f);
    u += 0x7FFFu + ((u >> 16) & 1u);   // RNE; finite inputs
    return (unsigned short)(u >> 16);
}

// --------------------------------------------------------------------------
// Single fused fp32->bf16 prepass: x (2M float4) | W_fc (1M) | W_proj (1M).
// 4096 blocks x 256 thr x 4 float4 = 4M float4 = 16M elements. Exact grid.
// --------------------------------------------------------------------------
__global__ void cvt_all(const float4* __restrict__ x,  ushort4* __restrict__ xb,
                        const float4* __restrict__ wf, ushort4* __restrict__ wfb,
                        const float4* __restrict__ wp, ushort4* __restrict__ wpb)
{
    const int base = blockIdx.x * 1024 + threadIdx.x;
    #pragma unroll
    for (int j = 0; j < 4; j++) {
        const int i = base + j * 256;
        const float4* s; ushort4* d; int k;
        if (i < (1 << 21))            { s = x;  d = xb;  k = i; }
        else if (i < 3 * (1 << 20))   { s = wf; d = wfb; k = i - (1 << 21); }
        else                          { s = wp; d = wpb; k = i - 3 * (1 << 20); }
        float4 v = s[k];
        ushort4 o;
        o.x = f2bf(v.x); o.y = f2bf(v.y); o.z = f2bf(v.z); o.w = f2bf(v.w);
        d[k] = o;
    }
}

// --------------------------------------------------------------------------
// C[M,N] = A[M,K] . B[N,K]^T  (bf16-as-ushort in, fp32 accum)
// RELU2: relu(v)^2 epilogue. OUT_BF16: bf16 store else fp32.
// m97 staging (global_load_lds w=16), BK=64: 8 staging loads/thread,
// 2 barriers + 32 MFMA per iteration.  Requires K%64==0.
// --------------------------------------------------------------------------
template<bool RELU2, bool OUT_BF16>
__global__ __launch_bounds__(256, 3)
void gemm_bt(const unsigned short* __restrict__ A,
             const unsigned short* __restrict__ B,
             void* __restrict__ Cv, int M, int N, int K)
{
    __shared__ unsigned short sA[BM * BK];   // 16 KiB row-major [128][64]
    __shared__ unsigned short sB[BN * BK];   // 16 KiB

    const int tid  = threadIdx.x;
    const int lane = tid & 63;
    const int wave = tid >> 6;
    const int wm   = (wave >> 1) * 64;
    const int wn   = (wave & 1) * 64;
    const int quad = lane >> 4;
    const int m16  = lane & 15;

    const long bm0 = (long)blockIdx.y * BM;
    const long bn0 = (long)blockIdx.x * BN;

    // staging: chunk c in [0,4): row = c*32 + tid/8, col = (tid&7)*8 elems.
    // LDS byte off = c*4096 + tid*16  (row*128 + col8*16 == c*4096 + 16*tid).
    const int srow = tid >> 3;                 // 0..31
    const int scol = (tid & 7) * 8;

    const unsigned short* gA = A + (bm0 + srow) * (long)K + scol;
    const unsigned short* gB = B + (bn0 + srow) * (long)K + scol;
    char* lA = (char*)sA + tid * 16;
    char* lB = (char*)sB + tid * 16;

    f32x4 acc[4][4];
    #pragma unroll
    for (int i = 0; i < 4; i++)
        #pragma unroll
        for (int j = 0; j < 4; j++)
            acc[i][j] = (f32x4)0.0f;

    for (int k0 = 0; k0 < K; k0 += BK) {
        #pragma unroll
        for (int c = 0; c < 4; c++)
            load16_to_lds(gA + (long)c * 32 * K + k0, lA + c * 4096);
        #pragma unroll
        for (int c = 0; c < 4; c++)
            load16_to_lds(gB + (long)c * 32 * K + k0, lB + c * 4096);
        __syncthreads();

        // two K=32 halves: 8 ds_read_b128 + 16 MFMA each
        #pragma unroll
        for (int h = 0; h < 2; h++) {
            bf16x8 af[4], bfr[4];
            #pragma unroll
            for (int i = 0; i < 4; i++)
                af[i]  = *(const bf16x8*)&sA[(wm + i * 16 + m16) * BK + h * 32 + quad * 8];
            #pragma unroll
            for (int j = 0; j < 4; j++)
                bfr[j] = *(const bf16x8*)&sB[(wn + j * 16 + m16) * BK + h * 32 + quad * 8];

            #pragma unroll
            for (int i = 0; i < 4; i++)
                #pragma unroll
                for (int j = 0; j < 4; j++)
                    acc[i][j] = __builtin_amdgcn_mfma_f32_16x16x32_bf16(
                        af[i], bfr[j], acc[i][j], 0, 0, 0);
        }
        __syncthreads();
    }

    // epilogue: C/D layout col=lane&15, row=quad*4+reg (m89/m91)
    #pragma unroll
    for (int i = 0; i < 4; i++) {
        #pragma unroll
        for (int j = 0; j < 4; j++) {
            #pragma unroll
            for (int r = 0; r < 4; r++) {
                float v = acc[i][j][r];
                if (RELU2) v = (v > 0.0f) ? v * v : 0.0f;
                const long row = bm0 + wm + i * 16 + quad * 4 + r;
                const long col = bn0 + wn + j * 16 + m16;
                if (OUT_BF16)
                    ((unsigned short*)Cv)[row * (long)N + col] = f2bf(v);
                else
                    ((float*)Cv)[row * (long)N + col] = v;
            }
        }
    }
}

extern "C" void kernel_launch(void* const* d_in, const int* in_sizes, int n_in,
                              void* d_out, int out_size, void* d_ws, size_t ws_size,
                              hipStream_t stream) {
    (void)in_sizes; (void)n_in; (void)out_size; (void)ws_size;

    const int T = 8192, DIM = 1024, HID = 4096;

    const float* x     = (const float*)d_in[0];  // [T, DIM]
    const float* W_fc  = (const float*)d_in[1];  // [HID, DIM]
    const float* W_prj = (const float*)d_in[2];  // [DIM, HID]
    float* out = (float*)d_out;                  // [T, DIM]

    char* ws = (char*)d_ws;
    unsigned short* h   = (unsigned short*)ws;                  // 64 MiB [T,HID]
    unsigned short* xb  = (unsigned short*)(ws + (64l << 20));  // 16 MiB
    unsigned short* wfb = (unsigned short*)(ws + (80l << 20));  //  8 MiB
    unsigned short* wpb = (unsigned short*)(ws + (88l << 20));  //  8 MiB

    // prepass: all three fp32 -> bf16 in ONE launch
    cvt_all<<<4096, 256, 0, stream>>>(
        (const float4*)x,     (ushort4*)xb,
        (const float4*)W_fc,  (ushort4*)wfb,
        (const float4*)W_prj, (ushort4*)wpb);

    // GEMM1: h = relu(x . W_fc^T)^2  [8192,4096] bf16
    gemm_bt<true, true><<<dim3(HID / BN, T / BM), dim3(256), 0, stream>>>(
        xb, wfb, h, T, HID, DIM);

    // GEMM2: out = h . W_proj^T      [8192,1024] fp32
    gemm_bt<false, false><<<dim3(DIM / BN, T / BM), dim3(256), 0, stream>>>(
        h, wpb, out, T, DIM, HID);
}